// Round 1
// baseline (66.980 us; speedup 1.0000x reference)
//
#include <hip/hip_runtime.h>

#define K1 17          // labels 0..16
#define NB 16          // batch
#define NC 4           // channels
#define NP 409600      // 640*640 pixels per image
#define NPV (NP / 4)   // float4 vectors per image
#define SIGMA_DIS 3.0f

// ---------------- Stage 1: per-(b,label) sum of squared norms + counts ----------------
__global__ __launch_bounds__(256) void seg_reduce_kernel(
    const float* __restrict__ pred,   // (NB, NC, NP)
    const int*   __restrict__ lab,    // (NB, NP)
    float* __restrict__ g_ss,         // (NB, K1)
    float* __restrict__ g_cnt)        // (NB, K1)
{
    __shared__ float ss_b[4][K1];
    __shared__ int   cnt_b[4][K1];

    const int tid  = threadIdx.x;
    const int wave = tid >> 6;
    const int b    = blockIdx.y;

    for (int e = tid; e < 4 * K1; e += 256) {
        (&ss_b[0][0])[e]  = 0.0f;
        (&cnt_b[0][0])[e] = 0;
    }
    __syncthreads();

    const float4* p0 = (const float4*)(pred + (size_t)(b * NC + 0) * NP);
    const float4* p1 = (const float4*)(pred + (size_t)(b * NC + 1) * NP);
    const float4* p2 = (const float4*)(pred + (size_t)(b * NC + 2) * NP);
    const float4* p3 = (const float4*)(pred + (size_t)(b * NC + 3) * NP);
    const int4*   lb = (const int4*)(lab + (size_t)b * NP);

    for (int v = blockIdx.x * 256 + tid; v < NPV; v += gridDim.x * 256) {
        float4 a = p0[v];
        float4 c = p1[v];
        float4 d = p2[v];
        float4 e = p3[v];
        int4   l = lb[v];

        float s0 = a.x * a.x + c.x * c.x + d.x * d.x + e.x * e.x;
        float s1 = a.y * a.y + c.y * c.y + d.y * d.y + e.y * e.y;
        float s2 = a.z * a.z + c.z * c.z + d.z * d.z + e.z * e.z;
        float s3 = a.w * a.w + c.w * c.w + d.w * d.w + e.w * e.w;

        unsafeAtomicAdd(&ss_b[wave][l.x], s0);
        unsafeAtomicAdd(&ss_b[wave][l.y], s1);
        unsafeAtomicAdd(&ss_b[wave][l.z], s2);
        unsafeAtomicAdd(&ss_b[wave][l.w], s3);
        atomicAdd(&cnt_b[wave][l.x], 1);
        atomicAdd(&cnt_b[wave][l.y], 1);
        atomicAdd(&cnt_b[wave][l.z], 1);
        atomicAdd(&cnt_b[wave][l.w], 1);
    }
    __syncthreads();

    if (tid < K1) {
        float s = ss_b[0][tid] + ss_b[1][tid] + ss_b[2][tid] + ss_b[3][tid];
        int   c = cnt_b[0][tid] + cnt_b[1][tid] + cnt_b[2][tid] + cnt_b[3][tid];
        unsafeAtomicAdd(&g_ss[b * K1 + tid], s);
        unsafeAtomicAdd(&g_cnt[b * K1 + tid], (float)c);
    }
}

// ---------------- Stage 2: pairwise loss over the (NB, K1) table ----------------
__global__ __launch_bounds__(512) void finalize_kernel(
    const float* __restrict__ g_ss,
    const float* __restrict__ g_cnt,
    float* __restrict__ out)
{
    __shared__ float m_sh[NB][K1];
    __shared__ float c_sh[NB][K1];
    __shared__ float inv_denom[NB];
    __shared__ float red[512];

    const int t = threadIdx.x;

    for (int e = t; e < NB * K1; e += 512) {
        float c = g_cnt[e];
        float s = g_ss[e];
        (&c_sh[0][0])[e] = c;
        (&m_sh[0][0])[e] = (c > 0.0f) ? s / (c * c) : 0.0f;
    }
    __syncthreads();

    if (t < NB) {
        int nk = 0;
        for (int k = K1 - 1; k >= 1; --k) {
            if (c_sh[t][k] > 0.0f) { nk = k; break; }
        }
        float denom = (float)(nk * (nk - 1));
        inv_denom[t] = (nk > 1) ? 1.0f / fmaxf(denom, 1.0f) : 0.0f;
    }
    __syncthreads();

    float acc = 0.0f;
    for (int e = t; e < NB * K1 * K1; e += 512) {
        int b  = e / (K1 * K1);
        int ij = e % (K1 * K1);
        int i  = ij / K1;
        int j  = ij % K1;
        if (i >= 1 && j > i && c_sh[b][i] > 0.0f && c_sh[b][j] > 0.0f) {
            float s2 = m_sh[b][i] + m_sh[b][j];
            float d  = sqrtf(s2);
            float x  = SIGMA_DIS - d;
            acc += log1pf(x * x) * inv_denom[b];
        }
    }

    red[t] = acc;
    __syncthreads();
    for (int s = 256; s > 0; s >>= 1) {
        if (t < s) red[t] += red[t + s];
        __syncthreads();
    }
    if (t == 0) out[0] = red[0];
}

extern "C" void kernel_launch(void* const* d_in, const int* in_sizes, int n_in,
                              void* d_out, int out_size, void* d_ws, size_t ws_size,
                              hipStream_t stream) {
    const float* pred = (const float*)d_in[0];
    const int*   lab  = (const int*)d_in[1];
    float* out = (float*)d_out;

    float* g_ss  = (float*)d_ws;
    float* g_cnt = g_ss + NB * K1;

    hipMemsetAsync(d_ws, 0, 2 * NB * K1 * sizeof(float), stream);

    dim3 grid(128, NB);
    seg_reduce_kernel<<<grid, 256, 0, stream>>>(pred, lab, g_ss, g_cnt);
    finalize_kernel<<<1, 512, 0, stream>>>(g_ss, g_cnt, out);
}

// Round 2
// 39.717 us; speedup vs baseline: 1.6864x; 1.6864x over previous
//
#include <hip/hip_runtime.h>

#define K  16          // tracked labels 1..16 (label 0 = background, never used in loss)
#define NB 16          // batch
#define NP 409600      // 640*640 pixels per image
#define NPV (NP / 4)   // float4 vectors per image
#define BX 64          // blocks per image
#define SIGMA_DIS 3.0f

// ---------------- Stage 1: per-(b,label) sum of squared norms + counts ----------------
// Per-thread register bins (no atomics); counts via wave-uniform ballot+popcount
// (scalar pipe). Block reduction: register-halving LDS tree, padded stride 17.
__global__ __launch_bounds__(256) void seg_reduce_kernel(
    const float* __restrict__ pred,   // (NB, 4, NP)
    const int*   __restrict__ lab,    // (NB, NP)
    float* __restrict__ partial)      // (NB*BX, 32): [0..15]=ss, [16..31]=cnt
{
    const int tid  = threadIdx.x;
    const int b    = blockIdx.y;
    const int bx   = blockIdx.x;
    const int lane = tid & 63;
    const int wave = tid >> 6;

    float ssb[K];
    int   cnt[K];
#pragma unroll
    for (int k = 0; k < K; ++k) { ssb[k] = 0.0f; cnt[k] = 0; }

    const float4* p0 = (const float4*)(pred + ((size_t)b * 4 + 0) * NP);
    const float4* p1 = (const float4*)(pred + ((size_t)b * 4 + 1) * NP);
    const float4* p2 = (const float4*)(pred + ((size_t)b * 4 + 2) * NP);
    const float4* p3 = (const float4*)(pred + ((size_t)b * 4 + 3) * NP);
    const int4*   lb = (const int4*)(lab + (size_t)b * NP);

    for (int v = bx * 256 + tid; v < NPV; v += BX * 256) {
        float4 a = p0[v];
        float4 c = p1[v];
        float4 d = p2[v];
        float4 e = p3[v];
        int4   l = lb[v];

        float s0 = a.x * a.x + c.x * c.x + d.x * d.x + e.x * e.x;
        float s1 = a.y * a.y + c.y * c.y + d.y * d.y + e.y * e.y;
        float s2 = a.z * a.z + c.z * c.z + d.z * d.z + e.z * e.z;
        float s3 = a.w * a.w + c.w * c.w + d.w * d.w + e.w * e.w;

#pragma unroll
        for (int k = 0; k < K; ++k) {
            const int kk = k + 1;
            bool e0 = (l.x == kk);
            bool e1 = (l.y == kk);
            bool e2 = (l.z == kk);
            bool e3 = (l.w == kk);
            ssb[k] += e0 ? s0 : 0.0f;
            ssb[k] += e1 ? s1 : 0.0f;
            ssb[k] += e2 ? s2 : 0.0f;
            ssb[k] += e3 ? s3 : 0.0f;
            // wave-uniform counts on the scalar pipe (vcc -> s_bcnt1 -> s_add)
            cnt[k] += __popcll(__ballot(e0)) + __popcll(__ballot(e1))
                    + __popcll(__ballot(e2)) + __popcll(__ballot(e3));
        }
    }

    // --- block reduction ---
    __shared__ float red_ss[128][K + 1];   // +1 pad: conflict-free banks
    __shared__ int   cnt_sh[4][K];

    if (lane == 0) {
#pragma unroll
        for (int k = 0; k < K; ++k) cnt_sh[wave][k] = cnt[k];
    }

    for (int s = 128; s >= 1; s >>= 1) {
        if (tid >= s && tid < 2 * s) {
#pragma unroll
            for (int k = 0; k < K; ++k) red_ss[tid - s][k] = ssb[k];
        }
        __syncthreads();
        if (tid < s) {
#pragma unroll
            for (int k = 0; k < K; ++k) ssb[k] += red_ss[tid][k];
        }
        __syncthreads();
    }

    if (tid == 0) {
        float* dst = partial + (size_t)(b * BX + bx) * 32;
#pragma unroll
        for (int k = 0; k < K; ++k) dst[k] = ssb[k];
#pragma unroll
        for (int k = 0; k < K; ++k)
            dst[16 + k] = (float)(cnt_sh[0][k] + cnt_sh[1][k] + cnt_sh[2][k] + cnt_sh[3][k]);
    }
}

// ---------------- Stage 2: combine partials + pairwise loss ----------------
__global__ __launch_bounds__(256) void finalize_kernel(
    const float* __restrict__ partial,
    float* __restrict__ out)
{
    __shared__ float m_sh[NB][K];
    __shared__ float c_sh[NB][K];
    __shared__ float inv_denom[NB];
    __shared__ float red[256];

    const int t = threadIdx.x;

    {   // one (b, k) per thread; t in [0,256) covers NB*K exactly
        const int b = t >> 4;
        const int k = t & 15;
        float ss = 0.0f, cc = 0.0f;
        const float* p = partial + (size_t)b * BX * 32 + k;
        for (int bx = 0; bx < BX; ++bx) {
            ss += p[bx * 32];
            cc += p[bx * 32 + 16];
        }
        c_sh[b][k] = cc;
        m_sh[b][k] = (cc > 0.0f) ? ss / (cc * cc) : 0.0f;
    }
    __syncthreads();

    if (t < NB) {
        int nk = 0;                        // nk = max label value present (bins are labels 1..16)
        for (int k = K; k >= 1; --k) {
            if (c_sh[t][k - 1] > 0.0f) { nk = k; break; }
        }
        float denom = (float)(nk * (nk - 1));
        inv_denom[t] = (nk > 1) ? 1.0f / fmaxf(denom, 1.0f) : 0.0f;
    }
    __syncthreads();

    float acc = 0.0f;
    for (int e = t; e < NB * K * K; e += 256) {   // 4096 items, 16 iters
        const int b  = e >> 8;
        const int ij = e & 255;
        const int ki = ij >> 4;            // label ki+1
        const int kj = ij & 15;            // label kj+1
        if (kj > ki && c_sh[b][ki] > 0.0f && c_sh[b][kj] > 0.0f) {
            float s2 = m_sh[b][ki] + m_sh[b][kj];
            float dd = sqrtf(s2);
            float x  = SIGMA_DIS - dd;
            acc += log1pf(x * x) * inv_denom[b];
        }
    }

    red[t] = acc;
    __syncthreads();
    for (int s = 128; s > 0; s >>= 1) {
        if (t < s) red[t] += red[t + s];
        __syncthreads();
    }
    if (t == 0) out[0] = red[0];
}

extern "C" void kernel_launch(void* const* d_in, const int* in_sizes, int n_in,
                              void* d_out, int out_size, void* d_ws, size_t ws_size,
                              hipStream_t stream) {
    const float* pred = (const float*)d_in[0];
    const int*   lab  = (const int*)d_in[1];
    float* out = (float*)d_out;

    float* partial = (float*)d_ws;   // NB*BX*32 floats = 128 KiB, written fully every call

    dim3 grid(BX, NB);
    seg_reduce_kernel<<<grid, 256, 0, stream>>>(pred, lab, partial);
    finalize_kernel<<<1, 256, 0, stream>>>(partial, out);
}